// Round 13
// baseline (495.117 us; speedup 1.0000x reference)
//
#include <hip/hip_runtime.h>
#include <hip/hip_bf16.h>
#include <stdint.h>

#define B_ 4
#define S_ 4096
#define E_ 1024
#define H_ 16
#define D_ 64
#define M_ (B_*S_)          // 16384 rows
constexpr float kEPS = 1e-6f;

typedef unsigned short u16;
typedef unsigned char  u8;
typedef __bf16 bf16x8 __attribute__((ext_vector_type(8)));
typedef float  f32x4  __attribute__((ext_vector_type(4)));
typedef u16    u16x8  __attribute__((ext_vector_type(8)));

typedef const __attribute__((address_space(1))) void* gaddr_t;
typedef __attribute__((address_space(3))) void*       laddr_t;

__device__ __forceinline__ u16 f2bf(float f) {
    union { float f; uint32_t u; } v; v.f = f;
    uint32_t u = v.u;
    u += 0x7fffu + ((u >> 16) & 1u);   // RNE
    return (u16)(u >> 16);
}
__device__ __forceinline__ float hi2f(uint32_t d) {
    union { uint32_t u; float f; } v; v.u = d & 0xffff0000u;
    return v.f;
}
__device__ __forceinline__ float lo2f(uint32_t d) {
    union { uint32_t u; float f; } v; v.u = d << 16;
    return v.f;
}

#define VM_WAIT(n) asm volatile("s_waitcnt vmcnt(" #n ")" ::: "memory")
#define LG0        asm volatile("s_waitcnt lgkmcnt(0)" ::: "memory")
#define SBAR       asm volatile("s_barrier" ::: "memory")

// ---------------- merged f32 -> bf16 conversion: 3 inputs ----------------
__global__ __launch_bounds__(256)
void cvt3_kernel(const float* __restrict__ s0, const float* __restrict__ s1,
                 const float* __restrict__ s2,
                 u16* __restrict__ d0, u16* __restrict__ d1, u16* __restrict__ d2,
                 int n4)
{
    const int z = blockIdx.y;
    const float* src = (z == 0) ? s0 : (z == 1) ? s1 : s2;
    u16*         dst = (z == 0) ? d0 : (z == 1) ? d1 : d2;
    const int stride = gridDim.x * blockDim.x;
    for (int i = blockIdx.x * blockDim.x + threadIdx.x; i < n4; i += stride) {
        float4 v = reinterpret_cast<const float4*>(src)[i];
        ushort4 o;
        o.x = f2bf(v.x); o.y = f2bf(v.y); o.z = f2bf(v.z); o.w = f2bf(v.w);
        reinterpret_cast<ushort4*>(dst)[i] = o;
    }
}

// ---------------- merged weight conversion: 4 weights ----------------
__global__ __launch_bounds__(256)
void cvtw_kernel(const float* __restrict__ w0, const float* __restrict__ w1,
                 const float* __restrict__ w2, const float* __restrict__ w3,
                 u16* __restrict__ o0, u16* __restrict__ o1,
                 u16* __restrict__ o2, u16* __restrict__ o3)
{
    const int z = blockIdx.y;
    const float* src = (z == 0) ? w0 : (z == 1) ? w1 : (z == 2) ? w2 : w3;
    u16*         dst = (z == 0) ? o0 : (z == 1) ? o1 : (z == 2) ? o2 : o3;
    const int i = blockIdx.x * blockDim.x + threadIdx.x;
    float4 v = reinterpret_cast<const float4*>(src)[i];
    ushort4 o;
    o.x = f2bf(v.x); o.y = f2bf(v.y); o.z = f2bf(v.z); o.w = f2bf(v.w);
    reinterpret_cast<ushort4*>(dst)[i] = o;
}

// ================= z-fused 8-phase 256x256 GEMM, C = A @ W^T =================
// NZ=3: one 256-block dispatch runs Q,K,V GEMMs back-to-back per block; the
// peeled last iteration of GEMM z stages tiles 0,1 of GEMM z+1 into the LDS
// regions freed phase-by-phase, so the pipeline never drains between z's.
// NZ=1: identical to the proven R9 schedule (final peel drains).
// epi: 0 = f32 out + bias; 1 = relu(x+b)+eps -> bf16; 2 = +mask -> bf16 transposed;
//      3 = x+b -> bf16 transposed
#define BM 256
#define BN 256
#define BKT 64
#define NKT (E_/BKT)        // 16 K-tiles

struct QKVArgs {
    const u16*   A[3];
    const u16*   W[3];
    const float* bias[3];
    const u8*    mask;
    u16*         C[3];
};

template<int NZ>
__global__ __launch_bounds__(512, 2)
void gemm8z(QKVArgs qa,
            const u16* __restrict__ A1, const u16* __restrict__ Bw1,
            const float* __restrict__ bias1, float* __restrict__ Cf)
{
    extern __shared__ u16 lds[];   // 65536 u16 = 128 KB
    const int tid  = threadIdx.x;
    const int wid  = tid >> 6, lane = tid & 63;
    const int wqr  = wid >> 2, wqc = wid & 3;
    const int m0   = blockIdx.x * BM;
    const int n0   = blockIdx.y * BN;
    const int fr   = lane & 15;
    const int cg   = lane >> 4;

    // ---- staging geometry ----
    const int srow = tid >> 3;
    const int ssc  = tid & 7;
    const int sck  = ssc ^ (srow & 7);
    const size_t aofs = (size_t)(m0 + srow)*E_ + sck*8;
    const size_t bofs = (size_t)(n0 + srow)*E_ + sck*8;
    const int sd0 = tid*8, sd1 = (tid + 512)*8;

    // ---- fragment read offsets ----
    int arow[4], brow[2];
#pragma unroll
    for (int mf = 0; mf < 4; ++mf) arow[mf] = (wqr*64 + mf*16 + fr) * 64;
#pragma unroll
    for (int nf = 0; nf < 2; ++nf) brow[nf] = (wqc*32 + nf*16 + fr) * 64;
    const int kx0 = ((cg)     ^ (fr & 7)) * 8;
    const int kx1 = ((4 + cg) ^ (fr & 7)) * 8;

    f32x4 acc[2][2][4][2] = {};
    bf16x8 afr[4][2];

    // ---- preload ALL biases (and mask words) so mid-z epilogues issue no loads ----
    float ba[NZ][2][2];
#pragma unroll
    for (int j = 0; j < NZ; ++j) {
        const float* bp = (NZ == 3)
            ? ((j == 0) ? qa.bias[0] : (j == 1) ? qa.bias[1] : qa.bias[2])
            : bias1;
#pragma unroll
        for (int nh = 0; nh < 2; ++nh)
#pragma unroll
            for (int nf = 0; nf < 2; ++nf)
                ba[j][nh][nf] = bp[n0 + nh*128 + wqc*32 + nf*16 + fr];
    }
    uint32_t mask_w[8] = {};
    if constexpr (NZ == 3) {
#pragma unroll
        for (int mh = 0; mh < 2; ++mh)
#pragma unroll
            for (int mf = 0; mf < 4; ++mf)
                mask_w[mh*4+mf] = *reinterpret_cast<const uint32_t*>(
                    qa.mask + m0 + mh*128 + wqr*64 + mf*16 + cg*4);
    }

    const u16* Acur = (NZ == 3) ? qa.A[0] : A1;
    const u16* Bcur = (NZ == 3) ? qa.W[0] : Bw1;

#define STG(AP, BP, BUF, MAT, HH, T) do { \
        u16* dst_ = lds + (BUF)*32768 + (MAT)*16384 + (HH)*8192; \
        const u16* src_ = ((MAT) ? ((BP) + bofs) : ((AP) + aofs)) \
                          + (size_t)(HH)*128*E_ + (size_t)(T)*BKT; \
        __builtin_amdgcn_global_load_lds((gaddr_t)(src_),                  (laddr_t)(dst_ + sd0), 16, 0, 0); \
        __builtin_amdgcn_global_load_lds((gaddr_t)(src_ + (size_t)64*E_), (laddr_t)(dst_ + sd1), 16, 0, 0); \
    } while (0)
#define STAGE(BUF, MAT, HH, T)  STG(Acur,  Bcur,  BUF, MAT, HH, T)
#define STAGEN(BUF, MAT, HH, T) STG(Anext, Bnext, BUF, MAT, HH, T)

#define PH(BUF, MH, NH, STG_STMT, WAIT_STMT) do { \
        const u16* Ab_ = lds + (BUF)*32768 + (MH)*8192; \
        const u16* Bb_ = lds + (BUF)*32768 + 16384 + (NH)*8192; \
        if ((NH) == 0) { \
            _Pragma("unroll") \
            for (int mf_ = 0; mf_ < 4; ++mf_) { \
                afr[mf_][0] = *reinterpret_cast<const bf16x8*>(Ab_ + arow[mf_] + kx0); \
                afr[mf_][1] = *reinterpret_cast<const bf16x8*>(Ab_ + arow[mf_] + kx1); \
            } \
        } \
        bf16x8 bfv[2][2]; \
        _Pragma("unroll") \
        for (int nf_ = 0; nf_ < 2; ++nf_) { \
            bfv[nf_][0] = *reinterpret_cast<const bf16x8*>(Bb_ + brow[nf_] + kx0); \
            bfv[nf_][1] = *reinterpret_cast<const bf16x8*>(Bb_ + brow[nf_] + kx1); \
        } \
        STG_STMT; \
        WAIT_STMT; \
        SBAR; \
        LG0; \
        __builtin_amdgcn_sched_barrier(0); \
        __builtin_amdgcn_s_setprio(1); \
        _Pragma("unroll") \
        for (int mf_ = 0; mf_ < 4; ++mf_) { \
            _Pragma("unroll") \
            for (int nf_ = 0; nf_ < 2; ++nf_) { \
                acc[MH][NH][mf_][nf_] = __builtin_amdgcn_mfma_f32_16x16x32_bf16(afr[mf_][0], bfv[nf_][0], acc[MH][NH][mf_][nf_], 0, 0, 0); \
                acc[MH][NH][mf_][nf_] = __builtin_amdgcn_mfma_f32_16x16x32_bf16(afr[mf_][1], bfv[nf_][1], acc[MH][NH][mf_][nf_], 0, 0, 0); \
            } \
        } \
        __builtin_amdgcn_s_setprio(0); \
        SBAR; \
    } while (0)

    // ---- prologue (z=0): tile0 fully into buf0, tile1 halves A0,B0 into buf1 ----
    STAGE(0, 0, 0, 0);
    STAGE(0, 1, 0, 0);
    STAGE(0, 0, 1, 0);
    STAGE(0, 1, 1, 0);
    STAGE(1, 0, 0, 1);
    STAGE(1, 1, 0, 1);
    VM_WAIT(4);
    SBAR;
    __builtin_amdgcn_sched_barrier(0);

#pragma unroll 1
    for (int z = 0; z < NZ; ++z) {
        const u16* Anext = Acur;
        const u16* Bnext = Bcur;
        if constexpr (NZ == 3) {
            Anext = (z == 0) ? qa.A[1] : qa.A[2];
            Bnext = (z == 0) ? qa.W[1] : qa.W[2];
        }

        // ---- main loop: tiles 0..13 computed, 1..15 staged ----
#pragma unroll 1
        for (int i = 0; i < 7; ++i) {
            const int T1 = 2*i + 1, T2 = 2*i + 2, T3 = 2*i + 3;
            PH(0, 0, 0, STAGE(1, 0, 1, T1), ;);
            PH(0, 0, 1, STAGE(1, 1, 1, T1), ;);
            PH(0, 1, 0, STAGE(0, 0, 0, T2), ;);
            PH(0, 1, 1, STAGE(0, 1, 0, T2), VM_WAIT(4));
            PH(1, 0, 0, STAGE(0, 0, 1, T2), ;);
            PH(1, 0, 1, STAGE(0, 1, 1, T2), ;);
            PH(1, 1, 0, STAGE(1, 0, 0, T3), ;);
            PH(1, 1, 1, STAGE(1, 1, 0, T3), VM_WAIT(4));
        }
        // ---- peel: compute tiles 14 (buf0), 15 (buf1) ----
        if (z < NZ - 1) {
            // cross-z: stage z+1's tiles 0,1 into the freed regions
            PH(0, 0, 0, STAGE(1, 0, 1, 15), ;);
            PH(0, 0, 1, STAGE(1, 1, 1, 15), ;);
            PH(0, 1, 0, STAGEN(0, 0, 0, 0), ;);
            PH(0, 1, 1, STAGEN(0, 1, 0, 0), VM_WAIT(4));   // drains T15 fully
            PH(1, 0, 0, STAGEN(0, 0, 1, 0), ;);
            PH(1, 0, 1, STAGEN(0, 1, 1, 0), ;);
            PH(1, 1, 0, STAGEN(1, 0, 0, 1), ;);
            PH(1, 1, 1, STAGEN(1, 1, 0, 1), VM_WAIT(4));   // drains T0'; leaves T1' A0,B0
        } else {
            PH(0, 0, 0, STAGE(1, 0, 1, 15), ;);
            PH(0, 0, 1, STAGE(1, 1, 1, 15), ;);
            PH(0, 1, 0, ;, ;);
            PH(0, 1, 1, ;, VM_WAIT(0));
            PH(1, 0, 0, ;, ;);
            PH(1, 0, 1, ;, ;);
            PH(1, 1, 0, ;, ;);
            PH(1, 1, 1, ;, ;);
        }

        // ---- epilogue for z (no vmem loads: bias/mask preloaded) ----
        const int epi = (NZ == 3) ? z + 1 : 0;
        u16* Cb = nullptr;
        if constexpr (NZ == 3)
            Cb = (z == 0) ? qa.C[0] : (z == 1) ? qa.C[1] : qa.C[2];
        float bcur[2][2];
#pragma unroll
        for (int nh = 0; nh < 2; ++nh)
#pragma unroll
            for (int nf = 0; nf < 2; ++nf)
                bcur[nh][nf] = (NZ == 1 || z == 0) ? ba[0][nh][nf]
                             : (NZ == 3 && z == 1) ? ba[NZ > 1 ? 1 : 0][nh][nf]
                                                   : ba[NZ > 2 ? 2 : 0][nh][nf];

        const int bblk = m0 >> 12;
        const int sloc = m0 & 4095;
#pragma unroll
        for (int mh = 0; mh < 2; ++mh) {
#pragma unroll
        for (int nh = 0; nh < 2; ++nh) {
#pragma unroll
        for (int mf = 0; mf < 4; ++mf) {
#pragma unroll
            for (int nf = 0; nf < 2; ++nf) {
                const int gn = n0 + nh*128 + wqc*32 + nf*16 + fr;
                const int mb = mh*128 + wqr*64 + mf*16 + cg*4;
                if (epi >= 2) {
                    ushort4 o;
#pragma unroll
                    for (int r = 0; r < 4; ++r) {
                        float x = acc[mh][nh][mf][nf][r] + bcur[nh][nf];
                        if (epi == 2) {
                            x = fmaxf(x, 0.f) + kEPS;
                            if ((mask_w[mh*4+mf] >> (r*8)) & 0xffu) x = 0.f;
                        }
                        ((u16*)&o)[r] = f2bf(x);
                    }
                    *reinterpret_cast<ushort4*>(Cb + ((size_t)(bblk*1024 + gn))*4096 + sloc + mb) = o;
                } else if (epi == 1) {
#pragma unroll
                    for (int r = 0; r < 4; ++r) {
                        const int gm = m0 + mb + r;
                        float x = acc[mh][nh][mf][nf][r] + bcur[nh][nf];
                        x = fmaxf(x, 0.f) + kEPS;
                        Cb[(size_t)gm*E_ + gn] = f2bf(x);
                    }
                } else {
#pragma unroll
                    for (int r = 0; r < 4; ++r) {
                        const int gm = m0 + mb + r;
                        Cf[(size_t)gm*E_ + gn] = acc[mh][nh][mf][nf][r] + bcur[nh][nf];
                    }
                }
            }
        }
        }
        }

        // ---- reset accumulators, advance pointers ----
        if (z < NZ - 1) {
#pragma unroll
            for (int a = 0; a < 2; ++a)
#pragma unroll
            for (int b = 0; b < 2; ++b)
#pragma unroll
            for (int c = 0; c < 4; ++c)
#pragma unroll
            for (int d = 0; d < 2; ++d)
                acc[a][b][c][d] = f32x4{0.f, 0.f, 0.f, 0.f};
            Acur = Anext;
            Bcur = Bnext;
        }
    }
#undef PH
#undef STAGE
#undef STAGEN
#undef STG
}

// ---- kv_context via MFMA: kvT[v][d] = sum_s VvT[v][s] * KaT[d][s] ----
#define NSC 8
#define KCH (S_/NSC)       // 512 s per block
__global__ __launch_bounds__(256)
void kv_mfma_kernel(const u16* __restrict__ KaT, const u16* __restrict__ VvT,
                    float* __restrict__ kvp, float* __restrict__ ksp)
{
    __shared__ float sm[4][64];
    const int bh = blockIdx.x, sc = blockIdx.y;
    const int tid = threadIdx.x;
    const int w = tid >> 6, lane = tid & 63;
    const int fr = lane & 15, cg = lane >> 4;

    const u16* Ar = VvT + ((size_t)bh*64 + w*16 + fr)*4096 + sc*KCH;
    const u16* Br0 = KaT + ((size_t)bh*64 + fr)*4096 + sc*KCH;

    f32x4 acc[4] = {};
#pragma unroll 2
    for (int ks = 0; ks < KCH/32; ++ks) {
        const int ko = ks*32 + cg*8;
        bf16x8 af = *reinterpret_cast<const bf16x8*>(Ar + ko);
#pragma unroll
        for (int nf = 0; nf < 4; ++nf) {
            bf16x8 bf = *reinterpret_cast<const bf16x8*>(Br0 + (size_t)nf*16*4096 + ko);
            acc[nf] = __builtin_amdgcn_mfma_f32_16x16x32_bf16(af, bf, acc[nf], 0, 0, 0);
        }
    }
    float* dst = kvp + ((size_t)sc*64 + bh)*4096;
#pragma unroll
    for (int nf = 0; nf < 4; ++nf)
#pragma unroll
        for (int r = 0; r < 4; ++r)
            dst[(w*16 + cg*4 + r)*64 + nf*16 + fr] = acc[nf][r];

    {
        const int d = tid & 63, qq = tid >> 6;
        const u16* kr = KaT + ((size_t)bh*64 + d)*4096 + sc*KCH + qq*(KCH/4);
        float s = 0.f;
#pragma unroll 4
        for (int i = 0; i < KCH/4/8; ++i) {
            bf16x8 kk = *reinterpret_cast<const bf16x8*>(kr + i*8);
#pragma unroll
            for (int j = 0; j < 8; ++j) s += (float)kk[j];
        }
        sm[qq][d] = s;
    }
    __syncthreads();
    if (tid < 64)
        ksp[((size_t)sc*64 + bh)*64 + tid] = sm[0][tid] + sm[1][tid] + sm[2][tid] + sm[3][tid];
}

// ---- reduce partials: kvT bf16 [bh][v][d] + ksum ----
__global__ __launch_bounds__(256)
void kv_reduce_kernel(const float* __restrict__ kvp, const float* __restrict__ ksp,
                      u16* __restrict__ kvT, float* __restrict__ ksum)
{
    const int i = blockIdx.x*256 + threadIdx.x;   // 262144
    float s = 0.f;
#pragma unroll
    for (int c = 0; c < NSC; ++c) s += kvp[(size_t)c*262144 + i];
    kvT[i] = f2bf(s);
    if (i < 4096) {
        float t = 0.f;
#pragma unroll
        for (int c = 0; c < NSC; ++c) t += ksp[(size_t)c*4096 + i];
        ksum[i] = t;
    }
}

// ---------------- stage 3: attn = (Qa @ kv) / max(Qa . ksum, eps), MFMA ----------------
__global__ __launch_bounds__(256)
void attn_kernel(const u16* __restrict__ Qa, const u16* __restrict__ kvT,
                 const float* __restrict__ ksum, u16* __restrict__ attn)
{
    __shared__ u16  Qs[256*64];
    __shared__ u16  Ts[64*64];
    __shared__ float kss[64];
    __shared__ float invd[256];

    const int bh = blockIdx.x, b = bh >> 4, h = bh & 15;
    const int s0 = blockIdx.y * 256;
    const int tid = threadIdx.x;
    const int wid = tid >> 6, lane = tid & 63;
    const int fr = lane & 15, cg = lane >> 4;

#pragma unroll
    for (int j = 0; j < 8; ++j) {
        int L = (wid*8 + j)*64 + lane;
        int row = L >> 3, c = L & 7;
        int cs = c ^ (row & 7);
        const u16* src = Qa + (size_t)(b*S_ + s0 + row)*E_ + h*64 + cs*8;
        __builtin_amdgcn_global_load_lds((gaddr_t)src, (laddr_t)(Qs + L*8), 16, 0, 0);
    }
#pragma unroll
    for (int k = 0; k < 2; ++k) {
        int g = k*256 + tid;
        int v = g >> 3, c = g & 7;
        uint4 q = *reinterpret_cast<const uint4*>(kvT + (size_t)bh*4096 + g*8);
        int cs = c ^ (v & 7);
        *reinterpret_cast<uint4*>(Ts + v*64 + cs*8) = q;
    }
    if (tid < 64) kss[tid] = ksum[bh*64 + tid];
    asm volatile("s_waitcnt vmcnt(0) lgkmcnt(0)" ::: "memory");
    __syncthreads();

    {
        float den = 0.f;
#pragma unroll
        for (int c = 0; c < 8; ++c) {
            uint4 qc = *reinterpret_cast<const uint4*>(Qs + tid*64 + (c ^ (tid & 7))*8);
            den += lo2f(qc.x)*kss[c*8+0] + hi2f(qc.x)*kss[c*8+1]
                 + lo2f(qc.y)*kss[c*8+2] + hi2f(qc.y)*kss[c*8+3]
                 + lo2f(qc.z)*kss[c*8+4] + hi2f(qc.z)*kss[c*8+5]
                 + lo2f(qc.w)*kss[c*8+6] + hi2f(qc.w)*kss[c*8+7];
        }
        invd[tid] = 1.0f / fmaxf(den, kEPS);
    }
    __syncthreads();

    f32x4 acc[4][4] = {};
#pragma unroll
    for (int ks = 0; ks < 2; ++ks) {
        bf16x8 bfrag[4];
#pragma unroll
        for (int nf = 0; nf < 4; ++nf) {
            int v = nf*16 + fr;
            bfrag[nf] = *reinterpret_cast<const bf16x8*>(Ts + v*64 + ((ks*4 + cg) ^ (v & 7))*8);
        }
#pragma unroll
        for (int mf = 0; mf < 4; ++mf) {
            int m = wid*64 + mf*16 + fr;
            bf16x8 afrag = *reinterpret_cast<const bf16x8*>(Qs + m*64 + ((ks*4 + cg) ^ (m & 7))*8);
#pragma unroll
            for (int nf = 0; nf < 4; ++nf)
                acc[mf][nf] = __builtin_amdgcn_mfma_f32_16x16x32_bf16(afrag, bfrag[nf], acc[mf][nf], 0, 0, 0);
        }
    }

#pragma unroll
    for (int mf = 0; mf < 4; ++mf) {
#pragma unroll
        for (int nf = 0; nf < 4; ++nf) {
            const int v = nf*16 + fr;
#pragma unroll
            for (int r = 0; r < 4; ++r) {
                const int row = wid*64 + mf*16 + cg*4 + r;
                float x = acc[mf][nf][r] * invd[row];
                attn[(size_t)(b*S_ + s0 + row)*E_ + h*64 + v] = f2bf(x);
            }
        }
    }
}

// ---------------- host ----------------
extern "C" void kernel_launch(void* const* d_in, const int* in_sizes, int n_in,
                              void* d_out, int out_size, void* d_ws, size_t ws_size,
                              hipStream_t stream)
{
    const float* query = (const float*)d_in[0];
    const float* key   = (const float*)d_in[1];
    const float* value = (const float*)d_in[2];
    const u8*    mask  = (const u8*)d_in[3];
    const float* Wq = (const float*)d_in[4];
    const float* bq = (const float*)d_in[5];
    const float* Wk = (const float*)d_in[6];
    const float* bk = (const float*)d_in[7];
    const float* Wv = (const float*)d_in[8];
    const float* bv = (const float*)d_in[9];
    const float* Wo = (const float*)d_in[10];
    const float* bo = (const float*)d_in[11];
    float* out = (float*)d_out;

    const size_t SZ_ME = (size_t)M_ * E_;
    const size_t SZ_EE = (size_t)E_ * E_;

    char* ws = (char*)d_ws;
    u16* qx   = (u16*)ws; ws += SZ_ME*2;   // query bf16; reused later for attnb
    u16* kx   = (u16*)ws; ws += SZ_ME*2;   // key bf16
    u16* vx   = (u16*)ws; ws += SZ_ME*2;   // value bf16
    u16* Qa   = (u16*)ws; ws += SZ_ME*2;
    u16* KaT  = (u16*)ws; ws += SZ_ME*2;   // [b*1024+h*64+d][4096] bf16
    u16* VvT  = (u16*)ws; ws += SZ_ME*2;   // [b*1024+h*64+v][4096] bf16
    u16* wqb  = (u16*)ws; ws += SZ_EE*2;
    u16* wkb  = (u16*)ws; ws += SZ_EE*2;
    u16* wvb  = (u16*)ws; ws += SZ_EE*2;
    u16* wob  = (u16*)ws; ws += SZ_EE*2;
    float* kvp = (float*)ws; ws += (size_t)NSC*64*4096*4;   // 8 MiB
    float* ksp = (float*)ws; ws += (size_t)NSC*4096*4;      // 128 KiB
    u16*  kvT  = (u16*)ws;  ws += (size_t)64*4096*2;        // 512 KiB
    float* ksum= (float*)ws; ws += 4096*4;

    u16* attnb = qx;   // overlay: qx dead after QKV gemm consumes it

    // 1) conversions to bf16 (2 dispatches)
    cvt3_kernel<<<dim3(2048, 3), 256, 0, stream>>>(query, key, value, qx, kx, vx, (int)(SZ_ME/4));
    cvtw_kernel<<<dim3(1024, 4), 256, 0, stream>>>(Wq, Wk, Wv, Wo, wqb, wkb, wvb, wob);

    // 2) QKV projections: ONE z-fused dispatch, 256 blocks = 1/CU
    QKVArgs qa;
    qa.A[0] = qx;  qa.A[1] = kx;  qa.A[2] = vx;
    qa.W[0] = wqb; qa.W[1] = wkb; qa.W[2] = wvb;
    qa.bias[0] = bq; qa.bias[1] = bk; qa.bias[2] = bv;
    qa.mask = mask;
    qa.C[0] = Qa; qa.C[1] = KaT; qa.C[2] = VvT;
    constexpr size_t LDS_BYTES = 2 * 32768 * sizeof(u16);   // 128 KB
    gemm8z<3><<<dim3(M_/BM, E_/BN), 512, LDS_BYTES, stream>>>(qa, nullptr, nullptr, nullptr, nullptr);

    // 3) kv_context + k_sum via MFMA (two-phase, deterministic)
    kv_mfma_kernel<<<dim3(64, NSC), 256, 0, stream>>>(KaT, VvT, kvp, ksp);
    kv_reduce_kernel<<<1024, 256, 0, stream>>>(kvp, ksp, kvT, ksum);

    // 4) attn numerator / denom (MFMA) -> attnb
    attn_kernel<<<dim3(B_*H_, S_/256), 256, 0, stream>>>(Qa, kvT, ksum, attnb);

    // 5) output projection -> f32 out
    QKVArgs dummy = {};
    dummy.mask = mask;
    gemm8z<1><<<dim3(M_/BM, E_/BN), 512, LDS_BYTES, stream>>>(dummy, attnb, wob, bo, out);
}

// Round 14
// 261.373 us; speedup vs baseline: 1.8943x; 1.8943x over previous
//
#include <hip/hip_runtime.h>
#include <hip/hip_bf16.h>
#include <stdint.h>

#define B_ 4
#define S_ 4096
#define E_ 1024
#define H_ 16
#define D_ 64
#define M_ (B_*S_)          // 16384 rows
constexpr float kEPS = 1e-6f;

typedef unsigned short u16;
typedef unsigned char  u8;
typedef __bf16 bf16x8 __attribute__((ext_vector_type(8)));
typedef float  f32x4  __attribute__((ext_vector_type(4)));
typedef u16    u16x8  __attribute__((ext_vector_type(8)));

typedef const __attribute__((address_space(1))) void* gaddr_t;
typedef __attribute__((address_space(3))) void*       laddr_t;

__device__ __forceinline__ u16 f2bf(float f) {
    union { float f; uint32_t u; } v; v.f = f;
    uint32_t u = v.u;
    u += 0x7fffu + ((u >> 16) & 1u);   // RNE
    return (u16)(u >> 16);
}
__device__ __forceinline__ float hi2f(uint32_t d) {
    union { uint32_t u; float f; } v; v.u = d & 0xffff0000u;
    return v.f;
}
__device__ __forceinline__ float lo2f(uint32_t d) {
    union { uint32_t u; float f; } v; v.u = d << 16;
    return v.f;
}

#define VM_WAIT(n) asm volatile("s_waitcnt vmcnt(" #n ")" ::: "memory")
#define LG0        asm volatile("s_waitcnt lgkmcnt(0)" ::: "memory")
#define SBAR       asm volatile("s_barrier" ::: "memory")

// ---------------- merged f32 -> bf16 conversion: 3 inputs ----------------
__global__ __launch_bounds__(256)
void cvt3_kernel(const float* __restrict__ s0, const float* __restrict__ s1,
                 const float* __restrict__ s2,
                 u16* __restrict__ d0, u16* __restrict__ d1, u16* __restrict__ d2,
                 int n4)
{
    const int z = blockIdx.y;
    const float* src = (z == 0) ? s0 : (z == 1) ? s1 : s2;
    u16*         dst = (z == 0) ? d0 : (z == 1) ? d1 : d2;
    const int stride = gridDim.x * blockDim.x;
    for (int i = blockIdx.x * blockDim.x + threadIdx.x; i < n4; i += stride) {
        float4 v = reinterpret_cast<const float4*>(src)[i];
        ushort4 o;
        o.x = f2bf(v.x); o.y = f2bf(v.y); o.z = f2bf(v.z); o.w = f2bf(v.w);
        reinterpret_cast<ushort4*>(dst)[i] = o;
    }
}

// ---------------- merged weight conversion: 4 weights ----------------
__global__ __launch_bounds__(256)
void cvtw_kernel(const float* __restrict__ w0, const float* __restrict__ w1,
                 const float* __restrict__ w2, const float* __restrict__ w3,
                 u16* __restrict__ o0, u16* __restrict__ o1,
                 u16* __restrict__ o2, u16* __restrict__ o3)
{
    const int z = blockIdx.y;
    const float* src = (z == 0) ? w0 : (z == 1) ? w1 : (z == 2) ? w2 : w3;
    u16*         dst = (z == 0) ? o0 : (z == 1) ? o1 : (z == 2) ? o2 : o3;
    const int i = blockIdx.x * blockDim.x + threadIdx.x;
    float4 v = reinterpret_cast<const float4*>(src)[i];
    ushort4 o;
    o.x = f2bf(v.x); o.y = f2bf(v.y); o.z = f2bf(v.z); o.w = f2bf(v.w);
    reinterpret_cast<ushort4*>(dst)[i] = o;
}

// ================= 8-phase 256x256 GEMM, deep-lead schedule (R10, best-known) =================
#define BM 256
#define BN 256
#define BKT 64
#define NKT (E_/BKT)        // 16 K-tiles

struct QKVArgs {
    const u16*   A[3];
    const u16*   W[3];
    const float* bias[3];
    const u8*    mask;
    u16*         C[3];
};

template<bool MERGED>
__global__ __launch_bounds__(512, 2)
void gemm8(QKVArgs qa,
           const u16* __restrict__ A1, const u16* __restrict__ Bw1,
           const float* __restrict__ bias1, float* __restrict__ Cf)
{
    extern __shared__ u16 lds[];   // 65536 u16 = 128 KB
    const int tid  = threadIdx.x;
    const int wid  = tid >> 6, lane = tid & 63;
    const int wqr  = wid >> 2, wqc = wid & 3;
    const int m0   = blockIdx.x * BM;
    const int n0   = blockIdx.y * BN;
    const int fr   = lane & 15;
    const int cg   = lane >> 4;

    const u16* A;  const u16* Bw;  const float* bias;  u16* Cb;  int epi;
    if constexpr (MERGED) {
        const int z = blockIdx.z;
        A = qa.A[z]; Bw = qa.W[z]; bias = qa.bias[z]; Cb = qa.C[z]; epi = z + 1;
    } else {
        A = A1; Bw = Bw1; bias = bias1; Cb = nullptr; epi = 0;
    }

    // ---- staging geometry ----
    const int srow = tid >> 3;
    const int ssc  = tid & 7;
    const int sck  = ssc ^ (srow & 7);
    const u16* aS = A  + (size_t)(m0 + srow)*E_ + sck*8;
    const u16* bS = Bw + (size_t)(n0 + srow)*E_ + sck*8;
    const int sd0 = tid*8, sd1 = (tid + 512)*8;

    // ---- fragment read offsets ----
    int arow[4], brow[2];
#pragma unroll
    for (int mf = 0; mf < 4; ++mf) arow[mf] = (wqr*64 + mf*16 + fr) * 64;
#pragma unroll
    for (int nf = 0; nf < 2; ++nf) brow[nf] = (wqc*32 + nf*16 + fr) * 64;
    const int kx0 = ((cg)     ^ (fr & 7)) * 8;
    const int kx1 = ((4 + cg) ^ (fr & 7)) * 8;

    f32x4 acc[2][2][4][2] = {};
    bf16x8 afr[4][2];
    bf16x8 bfr0[2][2], bfr1[2][2];   // B-frag caches: half0 / half1

    float bias_v[2][2];
#pragma unroll
    for (int nh = 0; nh < 2; ++nh)
#pragma unroll
        for (int nf = 0; nf < 2; ++nf)
            bias_v[nh][nf] = bias[n0 + nh*128 + wqc*32 + nf*16 + fr];

#define STAGE(BUF, MAT, HH, T) do { \
        u16* dst_ = lds + (BUF)*32768 + (MAT)*16384 + (HH)*8192; \
        const u16* src_ = ((MAT) ? bS : aS) + (size_t)(HH)*128*E_ + (size_t)(T)*BKT; \
        __builtin_amdgcn_global_load_lds((gaddr_t)(src_),                  (laddr_t)(dst_ + sd0), 16, 0, 0); \
        __builtin_amdgcn_global_load_lds((gaddr_t)(src_ + (size_t)64*E_), (laddr_t)(dst_ + sd1), 16, 0, 0); \
    } while (0)

#define PH(BUF, MH, NH, BFRX, LOADA, LOADB, STG_STMT, WAIT_STMT) do { \
        if (LOADA) { \
            const u16* Ab_ = lds + (BUF)*32768 + (MH)*8192; \
            _Pragma("unroll") \
            for (int mf_ = 0; mf_ < 4; ++mf_) { \
                afr[mf_][0] = *reinterpret_cast<const bf16x8*>(Ab_ + arow[mf_] + kx0); \
                afr[mf_][1] = *reinterpret_cast<const bf16x8*>(Ab_ + arow[mf_] + kx1); \
            } \
        } \
        if (LOADB) { \
            const u16* Bb_ = lds + (BUF)*32768 + 16384 + (NH)*8192; \
            _Pragma("unroll") \
            for (int nf_ = 0; nf_ < 2; ++nf_) { \
                BFRX[nf_][0] = *reinterpret_cast<const bf16x8*>(Bb_ + brow[nf_] + kx0); \
                BFRX[nf_][1] = *reinterpret_cast<const bf16x8*>(Bb_ + brow[nf_] + kx1); \
            } \
        } \
        STG_STMT; \
        WAIT_STMT; \
        SBAR; \
        LG0; \
        __builtin_amdgcn_sched_barrier(0); \
        __builtin_amdgcn_s_setprio(1); \
        _Pragma("unroll") \
        for (int mf_ = 0; mf_ < 4; ++mf_) { \
            _Pragma("unroll") \
            for (int nf_ = 0; nf_ < 2; ++nf_) { \
                acc[MH][NH][mf_][nf_] = __builtin_amdgcn_mfma_f32_16x16x32_bf16(afr[mf_][0], BFRX[nf_][0], acc[MH][NH][mf_][nf_], 0, 0, 0); \
                acc[MH][NH][mf_][nf_] = __builtin_amdgcn_mfma_f32_16x16x32_bf16(afr[mf_][1], BFRX[nf_][1], acc[MH][NH][mf_][nf_], 0, 0, 0); \
            } \
        } \
        __builtin_amdgcn_s_setprio(0); \
        SBAR; \
    } while (0)

    // ---- prologue: T0 fully + T1 fully; drain T0, leave T1's 8 in flight ----
    STAGE(0, 0, 0, 0); STAGE(0, 1, 0, 0);   // A0,B0(T0)
    STAGE(0, 1, 1, 0);                      // B1(T0)
    STAGE(0, 0, 1, 0);                      // A1(T0)
    STAGE(1, 0, 0, 1); STAGE(1, 1, 0, 1);   // A0,B0(T1)
    STAGE(1, 1, 1, 1);                      // B1(T1)
    STAGE(1, 0, 1, 1);                      // A1(T1)
    VM_WAIT(8);
    SBAR;
    __builtin_amdgcn_sched_barrier(0);

#pragma unroll 1
    for (int i = 0; i < 7; ++i) {
        const int T2 = 2*i + 2, T3 = 2*i + 3;
        PH(0, 0, 0, bfr0, 1, 1, ;,                                        VM_WAIT(10)); // ph1
        PH(0, 0, 1, bfr1, 0, 1, { STAGE(0,0,0,T2); STAGE(0,1,0,T2); },    VM_WAIT(12)); // ph2
        PH(0, 1, 0, bfr0, 1, 0, STAGE(0,1,1,T2),                          ;);           // ph3
        PH(0, 1, 1, bfr1, 0, 0, STAGE(0,0,1,T2),                          VM_WAIT(12)); // ph4
        PH(1, 0, 0, bfr0, 1, 1, ;,                                        VM_WAIT(10)); // ph5
        PH(1, 0, 1, bfr1, 0, 1, { STAGE(1,0,0,T3); STAGE(1,1,0,T3); },    VM_WAIT(12)); // ph6
        PH(1, 1, 0, bfr0, 1, 0, STAGE(1,1,1,T3),                          ;);           // ph7
        PH(1, 1, 1, bfr1, 0, 0, STAGE(1,0,1,T3),                          VM_WAIT(12)); // ph8
    }
    // ---- peeled last iter: tiles 14 (buf0), 15 (buf1); no staging ----
    PH(0, 0, 0, bfr0, 1, 1, ;, VM_WAIT(10));
    PH(0, 0, 1, bfr1, 0, 1, ;, VM_WAIT(8));
    PH(0, 1, 0, bfr0, 1, 0, ;, ;);
    PH(0, 1, 1, bfr1, 0, 0, ;, VM_WAIT(4));
    PH(1, 0, 0, bfr0, 1, 1, ;, VM_WAIT(2));
    PH(1, 0, 1, bfr1, 0, 1, ;, VM_WAIT(0));
    PH(1, 1, 0, bfr0, 1, 0, ;, ;);
    PH(1, 1, 1, bfr1, 0, 0, ;, ;);
#undef PH
#undef STAGE

    // ---- epilogue (runtime epi; wave-uniform branches) ----
    const int bblk = m0 >> 12;
    const int sloc = m0 & 4095;
#pragma unroll
    for (int mh = 0; mh < 2; ++mh) {
#pragma unroll
    for (int nh = 0; nh < 2; ++nh) {
#pragma unroll
    for (int mf = 0; mf < 4; ++mf) {
#pragma unroll
        for (int nf = 0; nf < 2; ++nf) {
            const int gn = n0 + nh*128 + wqc*32 + nf*16 + fr;
            const int mb = mh*128 + wqr*64 + mf*16 + cg*4;
            if (epi >= 2) {
                ushort4 o;
#pragma unroll
                for (int r = 0; r < 4; ++r) {
                    float x = acc[mh][nh][mf][nf][r] + bias_v[nh][nf];
                    if (epi == 2) {
                        x = fmaxf(x, 0.f) + kEPS;
                        if (qa.mask[m0 + mb + r]) x = 0.f;
                    }
                    ((u16*)&o)[r] = f2bf(x);
                }
                *reinterpret_cast<ushort4*>(Cb + ((size_t)(bblk*1024 + gn))*4096 + sloc + mb) = o;
            } else if (epi == 1) {
#pragma unroll
                for (int r = 0; r < 4; ++r) {
                    const int gm = m0 + mb + r;
                    float x = acc[mh][nh][mf][nf][r] + bias_v[nh][nf];
                    x = fmaxf(x, 0.f) + kEPS;
                    Cb[(size_t)gm*E_ + gn] = f2bf(x);
                }
            } else {
#pragma unroll
                for (int r = 0; r < 4; ++r) {
                    const int gm = m0 + mb + r;
                    Cf[(size_t)gm*E_ + gn] = acc[mh][nh][mf][nf][r] + bias_v[nh][nf];
                }
            }
        }
    }
    }
    }
}

// ---- kv_context via MFMA: kvT[v][d] = sum_s VvT[v][s] * KaT[d][s] ----
#define NSC 8
#define KCH (S_/NSC)       // 512 s per block
__global__ __launch_bounds__(256)
void kv_mfma_kernel(const u16* __restrict__ KaT, const u16* __restrict__ VvT,
                    float* __restrict__ kvp, float* __restrict__ ksp)
{
    __shared__ float sm[4][64];
    const int bh = blockIdx.x, sc = blockIdx.y;
    const int tid = threadIdx.x;
    const int w = tid >> 6, lane = tid & 63;
    const int fr = lane & 15, cg = lane >> 4;

    const u16* Ar = VvT + ((size_t)bh*64 + w*16 + fr)*4096 + sc*KCH;
    const u16* Br0 = KaT + ((size_t)bh*64 + fr)*4096 + sc*KCH;

    f32x4 acc[4] = {};
#pragma unroll 2
    for (int ks = 0; ks < KCH/32; ++ks) {
        const int ko = ks*32 + cg*8;
        bf16x8 af = *reinterpret_cast<const bf16x8*>(Ar + ko);
#pragma unroll
        for (int nf = 0; nf < 4; ++nf) {
            bf16x8 bf = *reinterpret_cast<const bf16x8*>(Br0 + (size_t)nf*16*4096 + ko);
            acc[nf] = __builtin_amdgcn_mfma_f32_16x16x32_bf16(af, bf, acc[nf], 0, 0, 0);
        }
    }
    float* dst = kvp + ((size_t)sc*64 + bh)*4096;
#pragma unroll
    for (int nf = 0; nf < 4; ++nf)
#pragma unroll
        for (int r = 0; r < 4; ++r)
            dst[(w*16 + cg*4 + r)*64 + nf*16 + fr] = acc[nf][r];

    {
        const int d = tid & 63, qq = tid >> 6;
        const u16* kr = KaT + ((size_t)bh*64 + d)*4096 + sc*KCH + qq*(KCH/4);
        float s = 0.f;
#pragma unroll 4
        for (int i = 0; i < KCH/4/8; ++i) {
            bf16x8 kk = *reinterpret_cast<const bf16x8*>(kr + i*8);
#pragma unroll
            for (int j = 0; j < 8; ++j) s += (float)kk[j];
        }
        sm[qq][d] = s;
    }
    __syncthreads();
    if (tid < 64)
        ksp[((size_t)sc*64 + bh)*64 + tid] = sm[0][tid] + sm[1][tid] + sm[2][tid] + sm[3][tid];
}

// ---- reduce partials: kvT bf16 [bh][v][d] + ksum ----
__global__ __launch_bounds__(256)
void kv_reduce_kernel(const float* __restrict__ kvp, const float* __restrict__ ksp,
                      u16* __restrict__ kvT, float* __restrict__ ksum)
{
    const int i = blockIdx.x*256 + threadIdx.x;   // 262144
    float s = 0.f;
#pragma unroll
    for (int c = 0; c < NSC; ++c) s += kvp[(size_t)c*262144 + i];
    kvT[i] = f2bf(s);
    if (i < 4096) {
        float t = 0.f;
#pragma unroll
        for (int c = 0; c < NSC; ++c) t += ksp[(size_t)c*4096 + i];
        ksum[i] = t;
    }
}

// ---------------- stage 3: attn = (Qa @ kv) / max(Qa . ksum, eps), MFMA ----------------
__global__ __launch_bounds__(256)
void attn_kernel(const u16* __restrict__ Qa, const u16* __restrict__ kvT,
                 const float* __restrict__ ksum, u16* __restrict__ attn)
{
    __shared__ u16  Qs[256*64];
    __shared__ u16  Ts[64*64];
    __shared__ float kss[64];
    __shared__ float invd[256];

    const int bh = blockIdx.x, b = bh >> 4, h = bh & 15;
    const int s0 = blockIdx.y * 256;
    const int tid = threadIdx.x;
    const int wid = tid >> 6, lane = tid & 63;
    const int fr = lane & 15, cg = lane >> 4;

#pragma unroll
    for (int j = 0; j < 8; ++j) {
        int L = (wid*8 + j)*64 + lane;
        int row = L >> 3, c = L & 7;
        int cs = c ^ (row & 7);
        const u16* src = Qa + (size_t)(b*S_ + s0 + row)*E_ + h*64 + cs*8;
        __builtin_amdgcn_global_load_lds((gaddr_t)src, (laddr_t)(Qs + L*8), 16, 0, 0);
    }
#pragma unroll
    for (int k = 0; k < 2; ++k) {
        int g = k*256 + tid;
        int v = g >> 3, c = g & 7;
        uint4 q = *reinterpret_cast<const uint4*>(kvT + (size_t)bh*4096 + g*8);
        int cs = c ^ (v & 7);
        *reinterpret_cast<uint4*>(Ts + v*64 + cs*8) = q;
    }
    if (tid < 64) kss[tid] = ksum[bh*64 + tid];
    asm volatile("s_waitcnt vmcnt(0) lgkmcnt(0)" ::: "memory");
    __syncthreads();

    {
        float den = 0.f;
#pragma unroll
        for (int c = 0; c < 8; ++c) {
            uint4 qc = *reinterpret_cast<const uint4*>(Qs + tid*64 + (c ^ (tid & 7))*8);
            den += lo2f(qc.x)*kss[c*8+0] + hi2f(qc.x)*kss[c*8+1]
                 + lo2f(qc.y)*kss[c*8+2] + hi2f(qc.y)*kss[c*8+3]
                 + lo2f(qc.z)*kss[c*8+4] + hi2f(qc.z)*kss[c*8+5]
                 + lo2f(qc.w)*kss[c*8+6] + hi2f(qc.w)*kss[c*8+7];
        }
        invd[tid] = 1.0f / fmaxf(den, kEPS);
    }
    __syncthreads();

    f32x4 acc[4][4] = {};
#pragma unroll
    for (int ks = 0; ks < 2; ++ks) {
        bf16x8 bfrag[4];
#pragma unroll
        for (int nf = 0; nf < 4; ++nf) {
            int v = nf*16 + fr;
            bfrag[nf] = *reinterpret_cast<const bf16x8*>(Ts + v*64 + ((ks*4 + cg) ^ (v & 7))*8);
        }
#pragma unroll
        for (int mf = 0; mf < 4; ++mf) {
            int m = wid*64 + mf*16 + fr;
            bf16x8 afrag = *reinterpret_cast<const bf16x8*>(Qs + m*64 + ((ks*4 + cg) ^ (m & 7))*8);
#pragma unroll
            for (int nf = 0; nf < 4; ++nf)
                acc[mf][nf] = __builtin_amdgcn_mfma_f32_16x16x32_bf16(afrag, bfrag[nf], acc[mf][nf], 0, 0, 0);
        }
    }

#pragma unroll
    for (int mf = 0; mf < 4; ++mf) {
#pragma unroll
        for (int nf = 0; nf < 4; ++nf) {
            const int v = nf*16 + fr;
#pragma unroll
            for (int r = 0; r < 4; ++r) {
                const int row = wid*64 + mf*16 + cg*4 + r;
                float x = acc[mf][nf][r] * invd[row];
                attn[(size_t)(b*S_ + s0 + row)*E_ + h*64 + v] = f2bf(x);
            }
        }
    }
}

// ---------------- host ----------------
extern "C" void kernel_launch(void* const* d_in, const int* in_sizes, int n_in,
                              void* d_out, int out_size, void* d_ws, size_t ws_size,
                              hipStream_t stream)
{
    const float* query = (const float*)d_in[0];
    const float* key   = (const float*)d_in[1];
    const float* value = (const float*)d_in[2];
    const u8*    mask  = (const u8*)d_in[3];
    const float* Wq = (const float*)d_in[4];
    const float* bq = (const float*)d_in[5];
    const float* Wk = (const float*)d_in[6];
    const float* bk = (const float*)d_in[7];
    const float* Wv = (const float*)d_in[8];
    const float* bv = (const float*)d_in[9];
    const float* Wo = (const float*)d_in[10];
    const float* bo = (const float*)d_in[11];
    float* out = (float*)d_out;

    const size_t SZ_ME = (size_t)M_ * E_;
    const size_t SZ_EE = (size_t)E_ * E_;

    char* ws = (char*)d_ws;
    u16* qx   = (u16*)ws; ws += SZ_ME*2;   // query bf16; reused later for attnb
    u16* kx   = (u16*)ws; ws += SZ_ME*2;   // key bf16
    u16* vx   = (u16*)ws; ws += SZ_ME*2;   // value bf16
    u16* Qa   = (u16*)ws; ws += SZ_ME*2;
    u16* KaT  = (u16*)ws; ws += SZ_ME*2;   // [b*1024+h*64+d][4096] bf16
    u16* VvT  = (u16*)ws; ws += SZ_ME*2;   // [b*1024+h*64+v][4096] bf16
    u16* wqb  = (u16*)ws; ws += SZ_EE*2;
    u16* wkb  = (u16*)ws; ws += SZ_EE*2;
    u16* wvb  = (u16*)ws; ws += SZ_EE*2;
    u16* wob  = (u16*)ws; ws += SZ_EE*2;
    float* kvp = (float*)ws; ws += (size_t)NSC*64*4096*4;   // 8 MiB
    float* ksp = (float*)ws; ws += (size_t)NSC*4096*4;      // 128 KiB
    u16*  kvT  = (u16*)ws;  ws += (size_t)64*4096*2;        // 512 KiB
    float* ksum= (float*)ws; ws += 4096*4;

    u16* attnb = qx;   // overlay: qx dead after QKV gemm consumes it

    // 1) conversions to bf16 (2 dispatches)
    cvt3_kernel<<<dim3(2048, 3), 256, 0, stream>>>(query, key, value, qx, kx, vx, (int)(SZ_ME/4));
    cvtw_kernel<<<dim3(1024, 4), 256, 0, stream>>>(Wq, Wk, Wv, Wo, wqb, wkb, wvb, wob);

    // 2) QKV projections: ONE dispatch, grid.z selects projection
    QKVArgs qa;
    qa.A[0] = qx;  qa.A[1] = kx;  qa.A[2] = vx;
    qa.W[0] = wqb; qa.W[1] = wkb; qa.W[2] = wvb;
    qa.bias[0] = bq; qa.bias[1] = bk; qa.bias[2] = bv;
    qa.mask = mask;
    qa.C[0] = Qa; qa.C[1] = KaT; qa.C[2] = VvT;
    dim3 ggrid(M_/BM, E_/BN, 3);
    constexpr size_t LDS_BYTES = 2 * 32768 * sizeof(u16);   // 128 KB
    gemm8<true><<<ggrid, 512, LDS_BYTES, stream>>>(qa, nullptr, nullptr, nullptr, nullptr);

    // 3) kv_context + k_sum via MFMA (two-phase, deterministic)
    kv_mfma_kernel<<<dim3(64, NSC), 256, 0, stream>>>(KaT, VvT, kvp, ksp);
    kv_reduce_kernel<<<1024, 256, 0, stream>>>(kvp, ksp, kvT, ksum);

    // 4) attn numerator / denom (MFMA) -> attnb
    attn_kernel<<<dim3(B_*H_, S_/256), 256, 0, stream>>>(Qa, kvT, ksum, attnb);

    // 5) output projection -> f32 out
    QKVArgs dummy = {};
    dummy.mask = mask;
    gemm8<false><<<dim3(M_/BM, E_/BN, 1), 512, LDS_BYTES, stream>>>(dummy, attnb, wob, bo, out);
}